// Round 5
// baseline (279.706 us; speedup 1.0000x reference)
//
#include <hip/hip_runtime.h>

// B=2048 rows, L=16384, W=30 sliding mean of sigmoid(x)*mask, per-row max.
// Barrier-free wave-private pipeline: each wave owns a quarter-row, 16 chunks
// of 256 starts, 2-deep global_load_lds prefetch with counted vmcnt.
constexpr int Bn      = 2048;
constexpr int L       = 16384;
constexpr int W       = 30;
constexpr int NT      = 256;            // 4 waves / block
constexpr int NWAVE   = NT / 64;        // 4
constexpr int QR      = L / NWAVE;      // 4096 elements per wave-region
constexpr int CH      = 256;            // window starts per chunk
constexpr int NCH     = QR / CH;        // 16 chunks per row per wave
constexpr int ROWS_PB = 2;              // rows per block -> grid 1024 = 4 blk/CU uniform
constexpr int NC      = NCH * ROWS_PB;  // 32 pipelined chunks per wave
constexpr int CELEM   = CH + 32;        // 288 staged floats (29 halo, 16B granule)
constexpr int SPL     = CH / 64;        // 4 starts per lane
constexpr int PSZ     = 360;            // padded prob slice: max index p(284)=355
constexpr int NBUF    = 3;              // compute c, in-flight c+1, c+2

typedef float f32x4 __attribute__((ext_vector_type(4)));

// HBM -> LDS DMA, 16B/lane, per-lane src, wave-uniform dest base (+lane*16).
#define GLDS(g, s) __builtin_amdgcn_global_load_lds(                          \
    (const __attribute__((address_space(1))) void*)(g),                       \
    (__attribute__((address_space(3))) void*)(s), 16, 0, 0)

__device__ __forceinline__ float sigp(float xv, float mv) {
    // m * 1/(1 + 2^(-x*log2(e)))
    float t = -1.44269504089f * xv;
    float e;
    asm("v_exp_f32 %0, %1" : "=v"(e) : "v"(t));
    return mv * __builtin_amdgcn_rcpf(1.0f + e);
}

__global__ __launch_bounds__(NT)
void winmax_pipe(const float* __restrict__ x, const float* __restrict__ m,
                 float* __restrict__ out) {
    // Per-wave private slices; GLDS dest must be linear (m104). prob padded
    // p(j)=j+(j>>2): window reads at 5l+const, odd stride -> conflict-free.
    __shared__ float rawx[NBUF][NWAVE][CELEM];   // 3*4*288*4 = 13824 B
    __shared__ float rawm[NBUF][NWAVE][CELEM];   // 13824 B
    __shared__ float prob[NWAVE][PSZ];           //  5760 B  => 33.4 KiB, 4 blk/CU

    const int t    = threadIdx.x;
    const int w    = t >> 6;
    const int l    = t & 63;
    const int row0 = blockIdx.x * ROWS_PB;
    const size_t wbase = (size_t)row0 * L + (size_t)w * QR;

    // Stage chunk c (0..NC-1) into buf b: ALWAYS 4 GLDS per wave (uniform
    // vmcnt). Guard (last wave, last chunk of a row): halo would read past
    // row end -> redirect src to an in-bounds dummy; compute forces those
    // prob entries to 0 (truncated windows are subsets of the window at
    // L-W, all terms >=0, so they can't win the max).
    auto stage = [&](int c, int b) {
        const size_t g = wbase + (size_t)(c >> 4) * L + (size_t)(c & 15) * CH;
        const float* gx = x + g;
        const float* gm = m + g;
        float* dx = &rawx[b][w][0];
        float* dm = &rawm[b][w][0];
        GLDS(gx + 4 * l, dx);
        GLDS(gm + 4 * l, dm);
        const bool guard = (w == NWAVE - 1) && ((c & 15) == NCH - 1);
        const float* hx = guard ? gx : gx + CH;   // dummy-but-in-bounds if guard
        const float* hm = guard ? gm : gm + CH;
        if (l < 8) {                               // 32-float halo (need 29)
            GLDS(hx + 4 * l, dx + CH);
            GLDS(hm + 4 * l, dm + CH);
        }
    };

    stage(0, 0);
    stage(1, 1);

    float best = 0.0f;
    int cb = 0;                                    // buffer holding chunk c
    #pragma unroll 1
    for (int c = 0; c < NC; ++c) {
        // Prefetch c+2, then drain ONLY chunk c (oldest 4 of 12) — never the
        // prefetches. Counts are wave-uniform by construction (4 GLDS/chunk).
        if (c + 2 < NC) {
            stage(c + 2, cb == 0 ? 2 : (cb == 1 ? 0 : 1));
            asm volatile("s_waitcnt vmcnt(8)" ::: "memory");
        } else if (c + 1 < NC) {
            asm volatile("s_waitcnt vmcnt(4)" ::: "memory");
        } else {
            asm volatile("s_waitcnt vmcnt(0)" ::: "memory");
        }
        __builtin_amdgcn_sched_barrier(0);         // rule #18: no hoisting past wait

        const float* rx = &rawx[cb][w][0];
        const float* rm = &rawm[cb][w][0];
        float* pw = &prob[w][0];

        // ---- sigp: raw -> padded prob (wave-private, no barrier needed) ----
        const f32x4 xv = *(const f32x4*)(rx + 4 * l);   // 16B-aligned ds_read_b128
        const f32x4 mv = *(const f32x4*)(rm + 4 * l);
        pw[5 * l + 0] = sigp(xv[0], mv[0]);             // p(4l+c)=5l+c, scalar b32
        pw[5 * l + 1] = sigp(xv[1], mv[1]);             // (5l odd stride: b128
        pw[5 * l + 2] = sigp(xv[2], mv[2]);             //  would be misaligned)
        pw[5 * l + 3] = sigp(xv[3], mv[3]);
        if (l < W - 1) {                                 // halo elements 256..284
            const bool zg = (w == NWAVE - 1) && ((c & 15) == NCH - 1);
            const float pe = zg ? 0.0f : sigp(rx[CH + l], rm[CH + l]);
            pw[320 + l + (l >> 2)] = pe;                 // p(256+l)
        }
        asm volatile("s_waitcnt lgkmcnt(0)" ::: "memory");  // wave's writes done
        __builtin_amdgcn_sched_barrier(0);

        // ---- sliding windows: lane l owns starts [4l, 4l+3] ----
        const int base = 5 * l;
        float keep[SPL - 1];
        float sum = 0.0f;
        #pragma unroll
        for (int cc = 0; cc < W; ++cc) {            // p-offsets compile-time
            const float v = pw[base + cc + (cc >> 2)];
            if (cc < SPL - 1) keep[cc] = v;
            sum += v;
        }
        float bb = sum;
        #pragma unroll
        for (int i = 1; i < SPL; ++i) {
            const int cc = W - 1 + i;
            sum += pw[base + cc + (cc >> 2)] - keep[i - 1];
            bb = fmaxf(bb, sum);
        }
        best = fmaxf(best, bb);

        // ---- row boundary: reduce wave, one atomic, reset ----
        if ((c & 15) == NCH - 1) {
            float r = best * (1.0f / W);
            #pragma unroll
            for (int off = 32; off > 0; off >>= 1)
                r = fmaxf(r, __shfl_down(r, off, 64));
            if (l == 0)
                atomicMax((unsigned int*)(out + row0 + (c >> 4)), __float_as_uint(r));
            best = 0.0f;
        }
        cb = (cb == 2) ? 0 : cb + 1;
    }
}

extern "C" void kernel_launch(void* const* d_in, const int* in_sizes, int n_in,
                              void* d_out, int out_size, void* d_ws, size_t ws_size,
                              hipStream_t stream) {
    const float* x = (const float*)d_in[0];
    const float* m = (const float*)d_in[1];
    float* out = (float*)d_out;
    // out is poisoned 0xAA (negative float as bits) -> must zero for atomicMax.
    hipMemsetAsync(out, 0, Bn * sizeof(float), stream);
    winmax_pipe<<<Bn / ROWS_PB, NT, 0, stream>>>(x, m, out);
}